// Round 1
// 399.953 us; speedup vs baseline: 1.3880x; 1.3880x over previous
//
#include <hip/hip_runtime.h>
#include <math.h>

#define TOKENS 16384
#define DIM    4096
#define NEXP   64
#define KSPLIT 4
#define KSLICE (DIM / KSPLIT)   // 1024
#define BK     32               // k per chunk (one MFMA K=32 worth of fp16 pairs)
#define NCHUNK (KSLICE / BK)    // 32
#define NCHUNK_G (DIM / BK)     // 128 global chunks (pack kernel covers full K)

typedef _Float16 f16x8 __attribute__((ext_vector_type(8)));
typedef float    f32x4 __attribute__((ext_vector_type(4)));

#define MFMA16(a, b, c) __builtin_amdgcn_mfma_f32_16x16x32_f16((a), (b), (c), 0, 0, 0)

// ---------------- Kernel 0: pack W into MFMA B-fragments (fp16 hi/lo split) ----
// Layout: wpk[c=0..127][t=0..3][lane=0..63][2] x 16B frags (hi, lo).
// Fragment convention (must match A-side in the GEMM): lane l supplies
// B[k = 8*(l>>4)+j][n = l&15] for j=0..7, i.e. 8 CONSECUTIVE k from row
// e=16t+(l&15) of W. Any HW-internal k-permutation cancels because A uses the
// same convention. Lo part scaled by 2^16 so it stays fp16-normal; |w|<2^-14
// guarded to 0 in hi (lo then captures all of w) so MFMA denormal-flush
// behavior cannot introduce error.
__global__ __launch_bounds__(256)
void pack_w_kernel(const float* __restrict__ w, uint4* __restrict__ wpk) {
    const int lane = threadIdx.x & 63;
    const int t    = threadIdx.x >> 6;     // expert tile 0..3
    const int c    = blockIdx.x;           // global k-chunk 0..127
    const int e    = 16 * t + (lane & 15);
    const int k0   = 32 * c + 8 * (lane >> 4);

    const float* src = w + (size_t)e * DIM + k0;
    const float4 v0 = *(const float4*)(src);
    const float4 v1 = *(const float4*)(src + 4);
    const float xs[8] = {v0.x, v0.y, v0.z, v0.w, v1.x, v1.y, v1.z, v1.w};

    f16x8 hi, lo;
#pragma unroll
    for (int j = 0; j < 8; ++j) {
        const float xv = xs[j];
        _Float16 h = (_Float16)xv;           // RNE
        float hf = (float)h;
        if (fabsf(xv) < 6.103515625e-05f) {  // below fp16 min normal: force hi=0
            h = (_Float16)0.f; hf = 0.f;
        }
        hi[j] = h;
        lo[j] = (_Float16)((xv - hf) * 65536.f);  // exact sub; scaled lo is normal
    }

    uint4* dst = wpk + ((size_t)(c * 4 + t) * 64 + lane) * 2;
    dst[0] = *(const uint4*)&hi;
    dst[1] = *(const uint4*)&lo;
}

// ---------------- Kernel 1: split-K router GEMM via fp16-split MFMA ----------
// grid 1024 = 256 token-blocks x KSPLIT, block 256 (4 waves, NO LDS/barriers).
// ks = bid&3: the 4 co-resident blocks per CU (bid += 256) share one W k-slice
// -> B-fragment loads are L1 hits. Wave wv owns tokens token0+16*wv..+15, all
// 64 experts (4 n-tiles). Per chunk: lane loads its own 32B of X (one cache
// line per token row per chunk), Dekker-splits to fp16 hi/lo in-register,
// 12x mfma_f32_16x16x32_f16. acc1 = xh*wh ; acc2 = xh*wl + xl*wh (lo terms
// pre-scaled 2^16); logit = acc1 + acc2*2^-16 -> error ~3*2^-22 per term,
// logit sigma ~7e-7 (fp32-reorder noise class -> top-2 indices stable).
// 2-chunk-deep X prefetch: 4 waves/SIMD x 2 chunks ~1120 cyc > ~900 cyc HBM.
__device__ __forceinline__ void do_chunk(const f16x8* __restrict__ b,
                                         const float4 rlo, const float4 rhi,
                                         f32x4 acc1[4], f32x4 acc2[4]) {
    // B fragments for this chunk: t stride = 128 f16x8, (hi,lo) adjacent
    const f16x8 bh0 = b[0],   bl0 = b[1];
    const f16x8 bh1 = b[128], bl1 = b[129];
    const f16x8 bh2 = b[256], bl2 = b[257];
    const f16x8 bh3 = b[384], bl3 = b[385];

    // A fragment: split this lane's 8 consecutive fp32 X values
    const float xs[8] = {rlo.x, rlo.y, rlo.z, rlo.w, rhi.x, rhi.y, rhi.z, rhi.w};
    f16x8 ah, al;
#pragma unroll
    for (int j = 0; j < 8; ++j) {
        const float xv = xs[j];
        const _Float16 h = (_Float16)xv;               // RNE; no guard needed on x
        ah[j] = h;
        al[j] = (_Float16)((xv - (float)h) * 65536.f); // exact sub, exact *2^16
    }

    acc1[0] = MFMA16(ah, bh0, acc1[0]);
    acc2[0] = MFMA16(ah, bl0, acc2[0]);
    acc2[0] = MFMA16(al, bh0, acc2[0]);
    acc1[1] = MFMA16(ah, bh1, acc1[1]);
    acc2[1] = MFMA16(ah, bl1, acc2[1]);
    acc2[1] = MFMA16(al, bh1, acc2[1]);
    acc1[2] = MFMA16(ah, bh2, acc1[2]);
    acc2[2] = MFMA16(ah, bl2, acc2[2]);
    acc2[2] = MFMA16(al, bh2, acc2[2]);
    acc1[3] = MFMA16(ah, bh3, acc1[3]);
    acc2[3] = MFMA16(ah, bl3, acc2[3]);
    acc2[3] = MFMA16(al, bh3, acc2[3]);
}

__global__ __launch_bounds__(256)
__attribute__((amdgpu_waves_per_eu(4, 4)))
void router_gemm_kernel(const float* __restrict__ x,
                        const f16x8* __restrict__ wpk,
                        float* __restrict__ part) {
    const int tid    = threadIdx.x;
    const int lane   = tid & 63;
    const int wv     = tid >> 6;
    const int bid    = blockIdx.x;
    const int ks     = bid & (KSPLIT - 1);  // co-resident blocks share ks
    const int tb     = bid >> 2;
    const int token0 = tb * 64 + wv * 16;

    // A side: lane l -> token row (l&15), k base 8*(l>>4) within the chunk
    const int row = token0 + (lane & 15);
    const float* xp = x + (size_t)row * DIM + ks * KSLICE + 8 * (lane >> 4);

    // B side: fragment stream for this ks slice; per-chunk stride 512 f16x8
    const f16x8* bp = wpk + (size_t)ks * NCHUNK * 512 + lane * 2;

    f32x4 acc1[4], acc2[4];
    const f32x4 zero = {0.f, 0.f, 0.f, 0.f};
#pragma unroll
    for (int t = 0; t < 4; ++t) { acc1[t] = zero; acc2[t] = zero; }

    // 2-deep X prefetch (chunks 0 and 1)
    float4 e0lo = *(const float4*)(xp);
    float4 e0hi = *(const float4*)(xp + 4);
    float4 e1lo = *(const float4*)(xp + BK);
    float4 e1hi = *(const float4*)(xp + BK + 4);

    for (int c = 0; c < NCHUNK; c += 2) {
        // even sub-iter: chunk c
        do_chunk(bp + (size_t)c * 512, e0lo, e0hi, acc1, acc2);
        if (c + 2 < NCHUNK) {
            e0lo = *(const float4*)(xp + (c + 2) * BK);
            e0hi = *(const float4*)(xp + (c + 2) * BK + 4);
        }
        // odd sub-iter: chunk c+1
        do_chunk(bp + (size_t)(c + 1) * 512, e1lo, e1hi, acc1, acc2);
        if (c + 3 < NCHUNK) {
            e1lo = *(const float4*)(xp + (c + 3) * BK);
            e1hi = *(const float4*)(xp + (c + 3) * BK + 4);
        }
    }

    // Epilogue: D lane map (HW-verified): m = 4*(l>>4)+r, n = l&15.
    // part[ks][token0 + 4*(l>>4) + r][16*t + (l&15)]
    float* pout = part + ((size_t)ks * TOKENS + token0 + 4 * (lane >> 4)) * NEXP
                + (lane & 15);
#pragma unroll
    for (int t = 0; t < 4; ++t) {
        const f32x4 v = acc1[t] + acc2[t] * (1.f / 65536.f);
#pragma unroll
        for (int r = 0; r < 4; ++r)
            pout[(size_t)r * NEXP + 16 * t] = v[r];
    }
}

// ---------------- Kernel 2: split-K reduce + top-2 + softmax ----------------
// One wave per token; lane == expert. Butterfly argmax twice (tiebreak: lower
// index). Indices written as float (harness reads d_out via the fp32 path).
__global__ __launch_bounds__(256)
void topk_kernel(const float* __restrict__ part, float* __restrict__ out) {
    const int lane  = threadIdx.x & 63;
    const int wv    = threadIdx.x >> 6;
    const int token = blockIdx.x * 4 + wv;

    float logit = 0.f;
#pragma unroll
    for (int s = 0; s < KSPLIT; ++s)
        logit += part[((size_t)s * TOKENS + token) * NEXP + lane];

    // top-1
    float v1 = logit; int i1 = lane;
#pragma unroll
    for (int off = 32; off > 0; off >>= 1) {
        const float ov = __shfl_xor(v1, off);
        const int   oi = __shfl_xor(i1, off);
        if (ov > v1 || (ov == v1 && oi < i1)) { v1 = ov; i1 = oi; }
    }
    // top-2: mask the winner
    float v2 = (lane == i1) ? -INFINITY : logit; int i2 = lane;
#pragma unroll
    for (int off = 32; off > 0; off >>= 1) {
        const float ov = __shfl_xor(v2, off);
        const int   oi = __shfl_xor(i2, off);
        if (ov > v2 || (ov == v2 && oi < i2)) { v2 = ov; i2 = oi; }
    }

    if (lane == 0) {
        const float e = expf(v2 - v1);       // <= 1, no overflow
        const float r = 1.f / (1.f + e);
        out[2 * token + 0] = r;              // score of top-1
        out[2 * token + 1] = e * r;          // score of top-2
        out[2 * TOKENS + 2 * token + 0] = (float)i1;
        out[2 * TOKENS + 2 * token + 1] = (float)i2;
    }
}

extern "C" void kernel_launch(void* const* d_in, const int* in_sizes, int n_in,
                              void* d_out, int out_size, void* d_ws, size_t ws_size,
                              hipStream_t stream) {
    const float* x = (const float*)d_in[0];   // (4,4096,4096) fp32
    const float* w = (const float*)d_in[1];   // (64,4096) fp32
    float* out  = (float*)d_out;              // 32768 scores + 32768 float-encoded indices
    float* part = (float*)d_ws;               // KSPLIT*TOKENS*NEXP*4 = 16.8 MB
    // packed W fragments right after part: 128*4*64*2*16B = 1 MB
    uint4* wpk = (uint4*)((char*)d_ws + (size_t)KSPLIT * TOKENS * NEXP * sizeof(float));

    pack_w_kernel<<<NCHUNK_G, 256, 0, stream>>>(w, wpk);
    router_gemm_kernel<<<(TOKENS / 64) * KSPLIT, 256, 0, stream>>>(
        x, (const f16x8*)wpk, part);
    topk_kernel<<<TOKENS / 4, 256, 0, stream>>>(part, out);
}